// Round 1
// baseline (297.152 us; speedup 1.0000x reference)
//
#include <hip/hip_runtime.h>
#include <math.h>

#define Hdim 2048
#define HF4  512            // Hdim/4
#define Edim 64
#define TB   64             // tokens per block
#define KB   64             // k-chunk in floats
#define NCH  (Hdim / KB)    // 32
#define MARGIN 2e-5f

typedef const __attribute__((address_space(1))) unsigned int ga_u32;
typedef __attribute__((address_space(3))) unsigned int la_u32;

__device__ __forceinline__ void gload16(const void* g, void* l) {
  __builtin_amdgcn_global_load_lds((ga_u32*)g, (la_u32*)l, 16, 0, 0);
}

// ---------------------------------------------------------------------------
// K1: fused fp32 logits GEMM + softmax + bias-top9 + margin flagging
// 256 threads, 64 tokens/block. LDS: A dbuf [2][64][16]f4 + B dbuf [2][64][16]f4 = 64 KB.
// XOR swizzle (row>>2)&7 applied to the GLOBAL source column and to the LDS read
// (linear LDS dest for global_load_lds — both-sides-or-neither rule).
// ---------------------------------------------------------------------------
__global__ __launch_bounds__(256, 2) void gate_main(
    const float* __restrict__ x, const float* __restrict__ wgt,
    const float* __restrict__ eb, float* __restrict__ out,
    int* __restrict__ fcnt, int* __restrict__ flist, int T)
{
  __shared__ float4 smem[4096];            // 64 KB
  const int t    = threadIdx.x;
  const int wv   = t >> 6;                 // wave 0..3
  const int ln   = t & 63;                 // lane
  const int tokb = blockIdx.x * TB;
  const int eg   = t & 15;                 // expert group (4 experts)
  const int tg   = t >> 4;                 // token group  (4 tokens)

  float acc[4][4];
  #pragma unroll
  for (int i = 0; i < 4; ++i)
    #pragma unroll
    for (int j = 0; j < 4; ++j) acc[i][j] = 0.f;

  const int swz_a = tg & 7;   // == (row>>2)&7 for rows 4*tg..4*tg+3
  const int swz_b = eg & 7;   // == (e>>2)&7  for e = 4*eg..4*eg+3

  for (int ch = 0; ch <= NCH; ++ch) {
    if (ch < NCH) {                        // stage chunk ch into buf ch&1
      const int k0 = ch * KB;
      float4* A = smem + (ch & 1) * 1024;
      float4* B = smem + 2048 + (ch & 1) * 1024;
      #pragma unroll
      for (int i = 0; i < 4; ++i) {
        const int r0  = wv * 16 + i * 4;             // 4 rows per instr
        const int sw  = (r0 >> 2) & 7;
        const int row = r0 + (ln >> 4);
        const int c4  = (ln & 15) ^ sw;              // pre-swizzled source col
        gload16(x   + (size_t)(tokb + row) * Hdim + k0 + c4 * 4, A + r0 * 16);
        gload16(wgt + (size_t)row          * Hdim + k0 + c4 * 4, B + r0 * 16);
      }
    }
    if (ch > 0) {                          // compute chunk ch-1 from buf (ch-1)&1
      const float4* A = smem + ((ch - 1) & 1) * 1024;
      const float4* B = smem + 2048 + ((ch - 1) & 1) * 1024;
      #pragma unroll 2
      for (int k4 = 0; k4 < 16; ++k4) {
        float4 av[4], bv[4];
        const int ka = k4 ^ swz_a;
        const int kb = k4 ^ swz_b;
        #pragma unroll
        for (int i = 0; i < 4; ++i) av[i] = A[(tg * 4 + i) * 16 + ka];
        #pragma unroll
        for (int j = 0; j < 4; ++j) bv[j] = B[(eg * 4 + j) * 16 + kb];
        #pragma unroll
        for (int i = 0; i < 4; ++i)
          #pragma unroll
          for (int j = 0; j < 4; ++j) {
            acc[i][j] = fmaf(av[i].x, bv[j].x, acc[i][j]);
            acc[i][j] = fmaf(av[i].y, bv[j].y, acc[i][j]);
            acc[i][j] = fmaf(av[i].z, bv[j].z, acc[i][j]);
            acc[i][j] = fmaf(av[i].w, bv[j].w, acc[i][j]);
          }
      }
    }
    asm volatile("s_waitcnt vmcnt(0)" ::: "memory");
    __syncthreads();
  }

  // ---- logits to LDS [64][68] (reuse smem) ----
  float* lg = (float*)smem;
  #pragma unroll
  for (int i = 0; i < 4; ++i)
    #pragma unroll
    for (int j = 0; j < 4; ++j)
      lg[(tg * 4 + i) * 68 + eg * 4 + j] = acc[i][j];
  __syncthreads();

  // ---- per-token softmax + top-9 (wave per token, lane = expert) ----
  const float bias = eb[ln];
  for (int s = 0; s < 16; ++s) {
    const int tok = wv * 16 + s;
    const float z = lg[tok * 68 + ln];
    float mx = z;
    #pragma unroll
    for (int off = 32; off; off >>= 1) mx = fmaxf(mx, __shfl_xor(mx, off, 64));
    const float p = expf(z - mx);
    float Zs = p;
    #pragma unroll
    for (int off = 32; off; off >>= 1) Zs += __shfl_xor(Zs, off, 64);
    const float sc  = p / Zs;          // original softmax score
    const float sco = sc;
    float bsw = sc + bias;             // bias-adjusted routing score
    float prev = 0.f, gmin = 1e30f, mys = 0.f;
    int myi = 0;
    #pragma unroll
    for (int r = 0; r < 9; ++r) {
      float v = bsw;
      int idx = ln;
      #pragma unroll
      for (int off = 32; off; off >>= 1) {       // argmax, ties -> lower index
        const float ov = __shfl_xor(v, off, 64);
        const int   oi = __shfl_xor(idx, off, 64);
        if (ov > v || (ov == v && oi < idx)) { v = ov; idx = oi; }
      }
      if (r) gmin = fminf(gmin, prev - v);
      prev = v;
      if (r < 8) {
        const float sv = __shfl(sco, idx, 64);
        if (ln == r)  { myi = idx; mys = sv; }
        if (ln == idx) bsw = -1e30f;
      }
    }
    float wsum = (ln < 8) ? mys : 0.f;
    #pragma unroll
    for (int off = 32; off; off >>= 1) wsum += __shfl_xor(wsum, off, 64);
    const int gt = tokb + tok;
    if (ln < 8) {
      out[(size_t)gt * 8 + ln] = (float)myi;                     // indices (as float)
      out[(size_t)T * 8 + (size_t)gt * 8 + ln] = mys / (wsum + 1e-20f);
    }
    if (gmin < MARGIN && ln == 0) {      // near-tie: needs fp64 re-decision
      const int pos = atomicAdd(fcnt, 1);
      flist[pos] = gt;
    }
  }
}

// ---------------------------------------------------------------------------
// K2: fp64 fixup for flagged tokens (4 tokens per block-iteration).
// ---------------------------------------------------------------------------
__global__ __launch_bounds__(256) void gate_fix(
    const float* __restrict__ x, const float* __restrict__ wgt,
    const float* __restrict__ eb, float* __restrict__ out,
    const int* __restrict__ fcnt, const int* __restrict__ flist, int T)
{
  __shared__ float4 xl[4 * HF4];           // 32 KB
  __shared__ double part[4][64][4];        // 8 KB
  __shared__ int tks[4];
  const int n = *fcnt;
  if (n <= 0) return;
  const int nb = (n + 3) >> 2;
  const int t = threadIdx.x;
  for (int b = blockIdx.x; b < nb; b += gridDim.x) {
    if (t < 4) {
      const int li = b * 4 + t;
      tks[t] = flist[li < n ? li : n - 1];     // clamp: benign duplicate work
    }
    __syncthreads();
    {
      const int m = t >> 6, l2 = t & 63;
      const float4* src = (const float4*)x + (size_t)tks[m] * HF4;
      #pragma unroll
      for (int ii = 0; ii < 8; ++ii) xl[m * HF4 + ii * 64 + l2] = src[ii * 64 + l2];
    }
    __syncthreads();
    const int e = t >> 2, q = t & 3;          // 64 experts x 4 k-quarters
    double acc[4] = {0.0, 0.0, 0.0, 0.0};
    const float4* w4 = (const float4*)wgt + (size_t)e * HF4;
    for (int c = 0; c < 128; ++c) {
      const int f4 = c * 4 + q;
      const float4 wvv = w4[f4];
      #pragma unroll
      for (int m = 0; m < 4; ++m) {
        const float4 xv = xl[m * HF4 + f4];
        acc[m] += (double)xv.x * (double)wvv.x + (double)xv.y * (double)wvv.y
                + (double)xv.z * (double)wvv.z + (double)xv.w * (double)wvv.w;
      }
    }
    #pragma unroll
    for (int m = 0; m < 4; ++m) part[m][e][q] = acc[m];
    __syncthreads();
    {
      const int m = t >> 6, ln = t & 63;      // wave m -> token m, lane = expert
      const double z = part[m][ln][0] + part[m][ln][1] + part[m][ln][2] + part[m][ln][3];
      double mx = z;
      #pragma unroll
      for (int off = 32; off; off >>= 1) mx = fmax(mx, __shfl_xor(mx, off, 64));
      const double p = exp(z - mx);
      double Zs = p;
      #pragma unroll
      for (int off = 32; off; off >>= 1) Zs += __shfl_xor(Zs, off, 64);
      const double sc  = p / Zs;
      const double sco = sc;
      double bsw = sc + (double)eb[ln];
      double mys = 0.0;
      int myi = 0;
      #pragma unroll
      for (int r = 0; r < 8; ++r) {
        double v = bsw;
        int idx = ln;
        #pragma unroll
        for (int off = 32; off; off >>= 1) {
          const double ov = __shfl_xor(v, off, 64);
          const int   oi = __shfl_xor(idx, off, 64);
          if (ov > v || (ov == v && oi < idx)) { v = ov; idx = oi; }
        }
        const double sv = __shfl(sco, idx, 64);
        if (ln == r)  { myi = idx; mys = sv; }
        if (ln == idx) bsw = -1.0e300;
      }
      double wsum = (ln < 8) ? mys : 0.0;
      #pragma unroll
      for (int off = 32; off; off >>= 1) wsum += __shfl_xor(wsum, off, 64);
      const int gt = tks[m];
      if (ln < 8) {
        out[(size_t)gt * 8 + ln] = (float)myi;
        out[(size_t)T * 8 + (size_t)gt * 8 + ln] = (float)(mys / (wsum + 1e-20));
      }
    }
    __syncthreads();
  }
}

extern "C" void kernel_launch(void* const* d_in, const int* in_sizes, int n_in,
                              void* d_out, int out_size, void* d_ws, size_t ws_size,
                              hipStream_t stream) {
  const float* x   = (const float*)d_in[0];
  const float* wgt = (const float*)d_in[1];
  const float* eb  = (const float*)d_in[2];
  float* out = (float*)d_out;
  const int T = in_sizes[0] / Hdim;          // 32768
  int* fcnt  = (int*)d_ws;
  int* flist = (int*)d_ws + 16;              // list starts at byte 64
  hipMemsetAsync(d_ws, 0, 64, stream);       // reset flag counter (capture-safe)
  hipLaunchKernelGGL(gate_main, dim3(T / TB), dim3(256), 0, stream,
                     x, wgt, eb, out, fcnt, flist, T);
  hipLaunchKernelGGL(gate_fix, dim3(256), dim3(256), 0, stream,
                     x, wgt, eb, out, fcnt, flist, T);
}